// Round 1
// baseline (2978.452 us; speedup 1.0000x reference)
//
#include <hip/hip_runtime.h>
#include <cstdint>
#include <cstddef>

#define WAYS  100
#define SHOTS 5
#define NQ    10000
#define DIM   2048
#define KSEL  512

#define BQ 64
#define BW 64
#define BK 32

struct Ctrl {
  double klsum[2];   // [0]=dctl, [1]=resl
  double wsum[2];
  float  w0[2];
  int    R, Dn;
  unsigned int T[8];
  int rem[8];
  int kk[8];
};

__device__ __forceinline__ unsigned int monokey(float f){
  unsigned int b = __float_as_uint(f);
  return (b & 0x80000000u) ? ~b : (b | 0x80000000u);
}

// ---- prototypes: mean over shots, then row l2-norm -------------------------
__global__ void proto_kernel(const float* __restrict__ xs, const float* __restrict__ dsh,
                             float* __restrict__ protoX, float* __restrict__ protoD){
  int b = blockIdx.x;
  const float* src = (b < WAYS) ? xs : dsh;
  float* dst = (b < WAYS) ? protoX : protoD;
  int w = (b < WAYS) ? b : b - WAYS;
  __shared__ float meanv[DIM];
  __shared__ float red[256];
  float loc = 0.f;
  for (int d = threadIdx.x; d < DIM; d += 256){
    float s = 0.f;
    for (int sh = 0; sh < SHOTS; sh++) s += src[((size_t)w*SHOTS + sh)*DIM + d];
    float m = s / (float)SHOTS;
    meanv[d] = m;
    loc += m*m;
  }
  red[threadIdx.x] = loc; __syncthreads();
  for (int st = 128; st > 0; st >>= 1){
    if (threadIdx.x < st) red[threadIdx.x] += red[threadIdx.x + st];
    __syncthreads();
  }
  float inv = 1.0f / fmaxf(sqrtf(red[0]), 1e-12f);
  for (int d = threadIdx.x; d < DIM; d += 256)
    dst[(size_t)w*DIM + d] = meanv[d] * inv;
}

// ---- per-query inverse L2 norm (folded into GEMM epilogue) -----------------
__global__ void invnorm_kernel(const float* __restrict__ xq, const float* __restrict__ dq,
                               float* __restrict__ invnX, float* __restrict__ invnD){
  int r = blockIdx.x;                       // 0..2*NQ-1
  const float* src = (r < NQ) ? xq : dq;
  float* dst = (r < NQ) ? invnX : invnD;
  int q = (r < NQ) ? r : r - NQ;
  const float4* row = (const float4*)(src + (size_t)q*DIM);
  float s = 0.f;
  for (int i = threadIdx.x; i < DIM/4; i += 64){
    float4 v = row[i];
    s += v.x*v.x + v.y*v.y + v.z*v.z + v.w*v.w;
  }
  for (int off = 32; off > 0; off >>= 1) s += __shfl_down(s, off);
  if (threadIdx.x == 0) dst[q] = 1.0f / fmaxf(sqrtf(s), 1e-12f);
}

// ---- GEMM: outL[q,w] = invn[row(q)] * dot(feat[row(q)], proto[w]) ----------
__global__ __launch_bounds__(256)
void gemm_logits(const float* __restrict__ feat, const float* __restrict__ proto,
                 const float* __restrict__ invn, const int* __restrict__ idxlist,
                 float* __restrict__ outL, const int* __restrict__ nDev, int nConst)
{
  int n = nDev ? *nDev : nConst;
  int qBase = blockIdx.x * BQ;
  if (qBase >= n) return;
  int wBase = blockIdx.y * BW;
  __shared__ float As[BK][BQ+4];
  __shared__ float Bs[BK][BW+4];
  int tid = threadIdx.x;
  int l0 = tid >> 3;            // 0..31
  int kv = tid & 7;             // 0..7
  int r0 = qBase + l0, r1 = qBase + l0 + 32;
  int gr0 = idxlist ? idxlist[min(r0, n-1)] : min(r0, n-1);
  int gr1 = idxlist ? idxlist[min(r1, n-1)] : min(r1, n-1);
  const float* pA0 = feat + (size_t)gr0*DIM + kv*4;
  const float* pA1 = feat + (size_t)gr1*DIM + kv*4;
  int w0i = wBase + l0, w1i = wBase + l0 + 32;
  const float* pB0 = proto + (size_t)w0i*DIM + kv*4;
  const float* pB1 = proto + (size_t)w1i*DIM + kv*4;
  bool bok0 = (w0i < WAYS), bok1 = (w1i < WAYS);
  int tx = tid & 15, ty = tid >> 4;
  float acc[4][4] = {};
  for (int k0 = 0; k0 < DIM; k0 += BK){
    float4 a0 = *(const float4*)(pA0 + k0);
    float4 a1 = *(const float4*)(pA1 + k0);
    float4 b0 = bok0 ? *(const float4*)(pB0 + k0) : make_float4(0.f,0.f,0.f,0.f);
    float4 b1 = bok1 ? *(const float4*)(pB1 + k0) : make_float4(0.f,0.f,0.f,0.f);
    __syncthreads();
    As[kv*4+0][l0]    = a0.x; As[kv*4+1][l0]    = a0.y; As[kv*4+2][l0]    = a0.z; As[kv*4+3][l0]    = a0.w;
    As[kv*4+0][l0+32] = a1.x; As[kv*4+1][l0+32] = a1.y; As[kv*4+2][l0+32] = a1.z; As[kv*4+3][l0+32] = a1.w;
    Bs[kv*4+0][l0]    = b0.x; Bs[kv*4+1][l0]    = b0.y; Bs[kv*4+2][l0]    = b0.z; Bs[kv*4+3][l0]    = b0.w;
    Bs[kv*4+0][l0+32] = b1.x; Bs[kv*4+1][l0+32] = b1.y; Bs[kv*4+2][l0+32] = b1.z; Bs[kv*4+3][l0+32] = b1.w;
    __syncthreads();
#pragma unroll
    for (int kk2 = 0; kk2 < BK; kk2++){
      float4 av = *(const float4*)&As[kk2][ty*4];
      float4 bv = *(const float4*)&Bs[kk2][tx*4];
      float a4[4] = {av.x, av.y, av.z, av.w};
      float b4[4] = {bv.x, bv.y, bv.z, bv.w};
#pragma unroll
      for (int i2 = 0; i2 < 4; i2++)
#pragma unroll
        for (int j2 = 0; j2 < 4; j2++)
          acc[i2][j2] += a4[i2]*b4[j2];
    }
  }
  for (int i2 = 0; i2 < 4; i2++){
    int q = qBase + ty*4 + i2;
    if (q >= n) continue;
    int gq = idxlist ? idxlist[q] : q;
    float s = invn[gq];
#pragma unroll
    for (int j2 = 0; j2 < 4; j2++){
      int w = wBase + tx*4 + j2;
      if (w < WAYS) outL[(size_t)q*WAYS + w] = acc[i2][j2] * s;
    }
  }
}

// ---- per-way L2 norm over the query dim ------------------------------------
__global__ void colnorm_kernel(const float* __restrict__ L, const int* __restrict__ nDev,
                               int nConst, float* __restrict__ colNorm){
  int w = blockIdx.x;
  int n = nDev ? *nDev : nConst;
  double s = 0.0;
  for (int q = threadIdx.x; q < n; q += 256){
    float v = L[(size_t)q*WAYS + w];
    s += (double)v * (double)v;
  }
  __shared__ double sd[256];
  sd[threadIdx.x] = s; __syncthreads();
  for (int st = 128; st > 0; st >>= 1){
    if (threadIdx.x < st) sd[threadIdx.x] += sd[threadIdx.x + st];
    __syncthreads();
  }
  if (threadIdx.x == 0) colNorm[w] = (float)sqrt(sd[0]);
}

__global__ void scale_kernel(float* __restrict__ L, const float* __restrict__ colNorm,
                             const float* __restrict__ tpPtr,
                             const int* __restrict__ nDev, int nConst){
  int n = nDev ? *nDev : nConst;
  size_t total = (size_t)n * WAYS;
  float tp = *tpPtr;
  for (size_t i = (size_t)blockIdx.x*blockDim.x + threadIdx.x; i < total;
       i += (size_t)gridDim.x*blockDim.x){
    int w = (int)(i % WAYS);
    L[i] = L[i] / (colNorm[w] + 1e-6f) * tp;
  }
}

// ---- per-row max/argmax (+ radix key) --------------------------------------
__global__ void rowstats1_kernel(const float* __restrict__ L, const int* __restrict__ nDev,
                                 int nConst, float* __restrict__ absCert,
                                 unsigned int* __restrict__ keys, int* __restrict__ pseudo){
  int n = nDev ? *nDev : nConst;
  int q = blockIdx.x*256 + threadIdx.x;
  if (q >= n) return;
  const float* row = L + (size_t)q*WAYS;
  float m = row[0]; int am = 0;
  for (int w = 1; w < WAYS; w++){ float v = row[w]; if (v > m){ m = v; am = w; } }
  absCert[q] = m; pseudo[q] = am; keys[q] = monokey(m);
}

// ---- per-row max + negative entropy (full runs only) -----------------------
__global__ void rowstats2_kernel(const float* __restrict__ L,
                                 float* __restrict__ absC, float* __restrict__ relC){
  int q = blockIdx.x*256 + threadIdx.x;
  if (q >= NQ) return;
  const float* row = L + (size_t)q*WAYS;
  float m = row[0];
  for (int w = 1; w < WAYS; w++) m = fmaxf(m, row[w]);
  float s = 0.f;
  for (int w = 0; w < WAYS; w++) s += expf(row[w] - m);
  float inv = 1.0f / s, rel = 0.f;
  for (int w = 0; w < WAYS; w++){
    float p = expf(row[w] - m) * inv;
    rel += p * logf(p + 1e-10f);
  }
  absC[q] = m; relC[q] = rel;
}

// ---- radix-select threshold for top-k --------------------------------------
__global__ __launch_bounds__(1024)
void select_kernel(const unsigned int* __restrict__ keys, const int* __restrict__ nDev,
                   int nConst, Ctrl* __restrict__ ctrl, int inst){
  int n = nDev ? *nDev : nConst;
  int k = n < KSEL ? n : KSEL;
  __shared__ int hist[256];
  __shared__ unsigned int sprefix;
  __shared__ int srem;
  if (threadIdx.x == 0){ sprefix = 0u; srem = k; }
  __syncthreads();
  for (int pass = 0; pass < 4; pass++){
    int shift = 24 - 8*pass;
    if (threadIdx.x < 256) hist[threadIdx.x] = 0;
    __syncthreads();
    unsigned int pref = sprefix;
    unsigned int mask = (pass == 0) ? 0u : (0xFFFFFFFFu << (shift + 8));
    for (int i = threadIdx.x; i < n; i += 1024){
      unsigned int key = keys[i];
      if ((key & mask) == pref) atomicAdd(&hist[(key >> shift) & 255], 1);
    }
    __syncthreads();
    if (threadIdx.x == 0){
      int acc = 0, rem = srem, sel = 0;
      for (int b2 = 255; b2 >= 0; b2--){
        int h = hist[b2];
        if (acc + h >= rem){ sel = b2; srem = rem - acc; break; }
        acc += h;
      }
      sprefix = pref | ((unsigned int)sel << shift);
    }
    __syncthreads();
  }
  if (threadIdx.x == 0){
    ctrl->T[inst] = sprefix;
    ctrl->rem[inst] = srem;
    ctrl->kk[inst] = k;
  }
}

// ---- deterministic stable gather of the top-k set --------------------------
__global__ __launch_bounds__(1024)
void gather_scan(const unsigned int* __restrict__ keys, const float* __restrict__ absCert,
                 const int* __restrict__ nDev, int nConst, const Ctrl* __restrict__ ctrl,
                 int inst, int* __restrict__ selIdx, float* __restrict__ selVal){
  int n = nDev ? *nDev : nConst;
  unsigned int T = ctrl->T[inst];
  int rem = ctrl->rem[inst], k = ctrl->kk[inst];
  int cntGT = k - rem;
  const int CH = 10;
  int t = threadIdx.x, q0 = t*CH;
  int fg[CH], fe[CH]; int cg = 0, ce = 0;
  for (int i = 0; i < CH; i++){
    int q = q0 + i; int g = 0, e = 0;
    if (q < n){ unsigned int key = keys[q]; g = key > T; e = (key == T); }
    fg[i] = g; fe[i] = e; cg += g; ce += e;
  }
  __shared__ int sG[1024], sE[1024];
  sG[t] = cg; sE[t] = ce; __syncthreads();
  for (int s = 1; s < 1024; s <<= 1){
    int vg = t >= s ? sG[t-s] : 0;
    int ve = t >= s ? sE[t-s] : 0;
    __syncthreads();
    sG[t] += vg; sE[t] += ve;
    __syncthreads();
  }
  int posG = sG[t] - cg, posE = sE[t] - ce;
  for (int i = 0; i < CH; i++){
    int q = q0 + i;
    if (q >= n) break;
    if (fg[i]){ selIdx[posG] = q; selVal[posG] = absCert[q]; posG++; }
    else if (fe[i]){
      if (posE < rem){ selIdx[cntGT+posE] = q; selVal[cntGT+posE] = absCert[q]; }
      posE++;
    }
  }
}

// ---- deterministic proto refine: protoRef = proto + segment sums -----------
__global__ void refine_kernel(const float* __restrict__ feat, const int* __restrict__ idxlist,
                              const float* __restrict__ invn, const float* __restrict__ proto,
                              const int* __restrict__ selIdx, const float* __restrict__ selVal,
                              const int* __restrict__ pseudo, const Ctrl* __restrict__ ctrl,
                              int inst, float* __restrict__ protoRef){
  int w = blockIdx.x;
  int k = ctrl->kk[inst];
  float acc[DIM/256];
#pragma unroll
  for (int i = 0; i < DIM/256; i++) acc[i] = 0.f;
  for (int j = 0; j < k; j++){
    int srow = selIdx[j];
    if (pseudo[srow] != w) continue;
    int grow = idxlist ? idxlist[srow] : srow;
    float coef = selVal[j] * invn[grow] / (float)k;
    const float* fr = feat + (size_t)grow*DIM;
#pragma unroll
    for (int i = 0; i < DIM/256; i++)
      acc[i] += coef * fr[threadIdx.x + i*256];
  }
  const float* pw = proto + (size_t)w*DIM;
  float* pr = protoRef + (size_t)w*DIM;
#pragma unroll
  for (int i = 0; i < DIM/256; i++)
    pr[threadIdx.x + i*256] = pw[threadIdx.x + i*256] + acc[i];
}

// ---- diff sign partition + index + w_r/w_f outputs -------------------------
__global__ __launch_bounds__(1024)
void diff_partition(const float* __restrict__ absCx, const float* __restrict__ relCx,
                    const float* __restrict__ absCd, const float* __restrict__ relCd,
                    Ctrl* __restrict__ ctrl, int* __restrict__ resIdx, int* __restrict__ dctIdx,
                    float* __restrict__ out){
  const int CH = 10;
  int t = threadIdx.x, q0 = t*CH;
  int fr[CH], fd[CH]; int cr = 0, cd = 0;
  for (int i = 0; i < CH; i++){
    int q = q0 + i; int r = 0, dn = 0;
    if (q < NQ){
      float dv = absCx[q] - absCd[q] + relCx[q] - relCd[q];
      r = dv > 0.f; dn = dv < 0.f;
    }
    fr[i] = r; fd[i] = dn; cr += r; cd += dn;
  }
  __shared__ int sR[1024], sD[1024];
  sR[t] = cr; sD[t] = cd; __syncthreads();
  for (int s = 1; s < 1024; s <<= 1){
    int vr = t >= s ? sR[t-s] : 0;
    int vd = t >= s ? sD[t-s] : 0;
    __syncthreads();
    sR[t] += vr; sD[t] += vd;
    __syncthreads();
  }
  int R = sR[1023], Dn = sD[1023];
  int posR = sR[t] - cr, posD = sD[t] - cd;
  if (t == 0){ ctrl->R = R; ctrl->Dn = Dn; }
  for (int i = 0; i < CH; i++){
    int q = q0 + i;
    if (q >= NQ) break;
    if (fr[i]){ resIdx[posR] = q; out[2+posR] = (float)q; posR++; }
    if (fd[i]){ dctIdx[posD] = q; out[2+R+posD] = (float)q; posD++; }
  }
  for (int q = t; q < NQ; q += 1024){
    float a = absCx[q], b = absCd[q];
    float den = fmaxf(a + b, 1e-8f);
    out[2+R+Dn+q]      = a / den;
    out[2+R+Dn+NQ+q]   = b / den;
  }
}

// ---- per-way logsumexp over the query dim ----------------------------------
__global__ void lse_kernel(const float* __restrict__ Lmat, const float* __restrict__ Hmat,
                           const int* __restrict__ nDev, float* __restrict__ lseL,
                           float* __restrict__ lseH){
  int b = blockIdx.x;                    // 0..199
  const float* M = (b < WAYS) ? Lmat : Hmat;
  int w = (b < WAYS) ? b : b - WAYS;
  int n = *nDev;
  float m = -1e30f; double s = 0.0;
  for (int q = threadIdx.x; q < n; q += 256){
    float v = M[(size_t)q*WAYS + w];
    if (v > m){ s = s*exp((double)(m - v)) + 1.0; m = v; }
    else s += exp((double)(v - m));
  }
  __shared__ float sm[256];
  __shared__ double ss[256];
  sm[threadIdx.x] = m; ss[threadIdx.x] = s; __syncthreads();
  for (int st = 128; st > 0; st >>= 1){
    if (threadIdx.x < st){
      float m1 = sm[threadIdx.x], m2 = sm[threadIdx.x+st];
      double s1 = ss[threadIdx.x], s2 = ss[threadIdx.x+st];
      float M2 = fmaxf(m1, m2);
      ss[threadIdx.x] = s1*exp((double)(m1-M2)) + s2*exp((double)(m2-M2));
      sm[threadIdx.x] = M2;
    }
    __syncthreads();
  }
  if (threadIdx.x == 0) ((b < WAYS) ? lseL : lseH)[w] = sm[0] + (float)log(ss[0]);
}

// ---- KL sum ----------------------------------------------------------------
__global__ void klsum_kernel(const float* __restrict__ L, const float* __restrict__ H,
                             const float* __restrict__ lseL, const float* __restrict__ lseH,
                             const int* __restrict__ nDev, double* __restrict__ accum){
  int n = *nDev;
  size_t total = (size_t)n * WAYS;
  double loc = 0.0;
  for (size_t i = (size_t)blockIdx.x*256 + threadIdx.x; i < total;
       i += (size_t)gridDim.x*256){
    int w = (int)(i % WAYS);
    float lh = H[i] - lseH[w];
    float ll = L[i] - lseL[w];
    loc += (double)(expf(lh) * (lh - ll));
  }
  __shared__ double sd[256];
  sd[threadIdx.x] = loc; __syncthreads();
  for (int st = 128; st > 0; st >>= 1){
    if (threadIdx.x < st) sd[threadIdx.x] += sd[threadIdx.x + st];
    __syncthreads();
  }
  if (threadIdx.x == 0) atomicAdd(accum, sd[0]);
}

__global__ void wsum_kernel(const float* __restrict__ absSrc, const int* __restrict__ idxlist,
                            const int* __restrict__ nDev, double* __restrict__ acc,
                            float* __restrict__ w0){
  int n = *nDev;
  double loc = 0.0;
  for (int i = blockIdx.x*256 + threadIdx.x; i < n; i += gridDim.x*256)
    loc += (double)absSrc[idxlist[i]];
  __shared__ double sd[256];
  sd[threadIdx.x] = loc; __syncthreads();
  for (int st = 128; st > 0; st >>= 1){
    if (threadIdx.x < st) sd[threadIdx.x] += sd[threadIdx.x + st];
    __syncthreads();
  }
  if (threadIdx.x == 0) atomicAdd(acc, sd[0]);
  if (blockIdx.x == 0 && threadIdx.x == 0) *w0 = absSrc[idxlist[0]];
}

__global__ void final_kernel(const Ctrl* __restrict__ ctrl, const float* __restrict__ tP,
                             const float* __restrict__ tdP, float* __restrict__ out){
  if (threadIdx.x == 0 && blockIdx.x == 0){
    float lossd = ctrl->w0[0] * (float)ctrl->klsum[0] / ((float)ctrl->wsum[0] + 1e-8f);
    float lossr = ctrl->w0[1] * (float)ctrl->klsum[1] / ((float)ctrl->wsum[1] + 1e-8f);
    out[0] = (*tP)  * lossr;   // temp * loss_resl
    out[1] = (*tdP) * lossd;   // temp_dct * loss_dctl
  }
}

extern "C" void kernel_launch(void* const* d_in, const int* in_sizes, int n_in,
                              void* d_out, int out_size, void* d_ws, size_t ws_size,
                              hipStream_t stream)
{
  const float* xs  = (const float*)d_in[0];
  const float* xq  = (const float*)d_in[1];
  const float* dsh = (const float*)d_in[2];
  const float* dq  = (const float*)d_in[3];
  const float* tpP = (const float*)d_in[4];
  const float* tP  = (const float*)d_in[5];
  const float* tdP = (const float*)d_in[6];
  float* out = (float*)d_out;

  char* base = (char*)d_ws;
  Ctrl* ctrl = (Ctrl*)base;
  size_t off = 1024;
  auto alloc = [&](size_t nElem)->void*{ void* p = base + off; off += nElem*4; return p; };
  float* protoX   = (float*)alloc((size_t)WAYS*DIM);
  float* protoD   = (float*)alloc((size_t)WAYS*DIM);
  float* protoRef = (float*)alloc((size_t)WAYS*DIM);
  float* invnX    = (float*)alloc(NQ);
  float* invnD    = (float*)alloc(NQ);
  float* absCx    = (float*)alloc(NQ);
  float* relCx    = (float*)alloc(NQ);
  float* absCd    = (float*)alloc(NQ);
  float* relCd    = (float*)alloc(NQ);
  float* absCert  = (float*)alloc(NQ);
  unsigned int* keys = (unsigned int*)alloc(NQ);
  int*   pseudo   = (int*)alloc(NQ);
  float* colNorm  = (float*)alloc(WAYS);
  float* lseL     = (float*)alloc(WAYS);
  float* lseH     = (float*)alloc(WAYS);
  float* selVal   = (float*)alloc(KSEL);
  int*   selIdx   = (int*)alloc(KSEL);
  int*   resIdx   = (int*)alloc(NQ);
  int*   dctIdx   = (int*)alloc(NQ);
  float* logitsS  = (float*)alloc((size_t)NQ*WAYS);
  float* bufA     = (float*)alloc((size_t)NQ*WAYS);
  float* bufB     = (float*)alloc((size_t)NQ*WAYS);
  if (off > ws_size) return;   // insufficient scratch — bail

  hipMemsetAsync(ctrl, 0, sizeof(Ctrl), stream);
  proto_kernel<<<2*WAYS, 256, 0, stream>>>(xs, dsh, protoX, protoD);
  invnorm_kernel<<<2*NQ, 64, 0, stream>>>(xq, dq, invnX, invnD);

  dim3 ggrid((NQ + BQ - 1)/BQ, (WAYS + BW - 1)/BW);

  auto run_distance = [&](const float* feat, const float* invn, const float* proto,
                          const int* idxlist, const int* nDev, int nConst,
                          float* Lbuf, int inst){
    gemm_logits<<<ggrid,256,0,stream>>>(feat, proto, invn, idxlist, Lbuf, nDev, nConst);
    colnorm_kernel<<<WAYS,256,0,stream>>>(Lbuf, nDev, nConst, colNorm);
    scale_kernel<<<1024,256,0,stream>>>(Lbuf, colNorm, tpP, nDev, nConst);
    rowstats1_kernel<<<(NQ+255)/256,256,0,stream>>>(Lbuf, nDev, nConst, absCert, keys, pseudo);
    select_kernel<<<1,1024,0,stream>>>(keys, nDev, nConst, ctrl, inst);
    gather_scan<<<1,1024,0,stream>>>(keys, absCert, nDev, nConst, ctrl, inst, selIdx, selVal);
    refine_kernel<<<WAYS,256,0,stream>>>(feat, idxlist, invn, proto, selIdx, selVal, pseudo,
                                         ctrl, inst, protoRef);
    gemm_logits<<<ggrid,256,0,stream>>>(feat, protoRef, invn, idxlist, Lbuf, nDev, nConst);
    colnorm_kernel<<<WAYS,256,0,stream>>>(Lbuf, nDev, nConst, colNorm);
    scale_kernel<<<1024,256,0,stream>>>(Lbuf, colNorm, tpP, nDev, nConst);
  };

  // full runs -> abs/rel certainties
  run_distance(xq, invnX, protoX, nullptr, nullptr, NQ, logitsS, 0);
  rowstats2_kernel<<<(NQ+255)/256,256,0,stream>>>(logitsS, absCx, relCx);
  run_distance(dq, invnD, protoD, nullptr, nullptr, NQ, logitsS, 1);
  rowstats2_kernel<<<(NQ+255)/256,256,0,stream>>>(logitsS, absCd, relCd);

  diff_partition<<<1,1024,0,stream>>>(absCx, relCx, absCd, relCd, ctrl, resIdx, dctIdx, out);

  // loss_dctl = distill(ldl, lrh, absCx[res])
  run_distance(xq, invnX, protoX, resIdx, &ctrl->R, 0, bufA, 2);   // lrh
  run_distance(dq, invnD, protoD, resIdx, &ctrl->R, 0, bufB, 3);   // ldl
  lse_kernel<<<2*WAYS,256,0,stream>>>(bufB, bufA, &ctrl->R, lseL, lseH);
  klsum_kernel<<<256,256,0,stream>>>(bufB, bufA, lseL, lseH, &ctrl->R, &ctrl->klsum[0]);
  wsum_kernel<<<(NQ+255)/256,256,0,stream>>>(absCx, resIdx, &ctrl->R, &ctrl->wsum[0], &ctrl->w0[0]);

  // loss_resl = distill(lrl, ldh, absCd[dct])
  run_distance(dq, invnD, protoD, dctIdx, &ctrl->Dn, 0, bufA, 4);  // ldh
  run_distance(xq, invnX, protoX, dctIdx, &ctrl->Dn, 0, bufB, 5);  // lrl
  lse_kernel<<<2*WAYS,256,0,stream>>>(bufB, bufA, &ctrl->Dn, lseL, lseH);
  klsum_kernel<<<256,256,0,stream>>>(bufB, bufA, lseL, lseH, &ctrl->Dn, &ctrl->klsum[1]);
  wsum_kernel<<<(NQ+255)/256,256,0,stream>>>(absCd, dctIdx, &ctrl->Dn, &ctrl->wsum[1], &ctrl->w0[1]);

  final_kernel<<<1,64,0,stream>>>(ctrl, tP, tdP, out);
}